// Round 15
// baseline (183.381 us; speedup 1.0000x reference)
//
#include <hip/hip_runtime.h>

// Problem constants (B=8, Tq=Tv=512, D=512, U=128)
constexpr int Bb = 8;
constexpr int Tq = 512;
constexpr int Tv = 512;
constexpr int Dd = 512;
constexpr int Uu = 128;
constexpr float C2LOG2E = 2.88539008177792681f;   // 2*log2(e)

typedef float v2f __attribute__((ext_vector_type(2)));

// ---------------------------------------------------------------------------
// Kernel A (R14 body, byte-identical -- best measured): projections +
// V-compaction, 16 rows/block, 1024 threads, 512 blocks. s_load x-fragments,
// float2 W, 8-way LDS reduce, Eq/Ek = exp2(2log2e*proj), kT compact
// u4-interleaved, vc dense compact V with zeroed tail rows, cnt_g export.
// ---------------------------------------------------------------------------
__global__ __launch_bounds__(1024, 8) void proj_kernel(
    const float* __restrict__ query,
    const float* __restrict__ key,
    const float* __restrict__ value,
    const float* __restrict__ Wa,
    const float* __restrict__ Ua,
    const int* __restrict__ mask,
    float* __restrict__ qf2, float* __restrict__ kT,
    float* __restrict__ vc, int* __restrict__ cnt_g)
{
    const int R    = blockIdx.x * 16;              // 0..8191
    const bool isQ = R < Bb * Tq;
    const float* __restrict__ src = isQ ? query : key;
    const float* __restrict__ W   = isQ ? Wa : Ua;
    const int Rloc = isQ ? R : R - Bb * Tq;        // 0..4095

    __shared__ float part[8 * 16 * 128];           // 64 KB: part[dq][r][u]
    __shared__ int posLoc[16];
    __shared__ int cntS;
    const int t = threadIdx.x;                     // 0..1023

    if (!isQ && t < 64) {                          // wave-0 ballot scan -> pos
        const int b  = Rloc >> 9;
        const int j0 = Rloc & 511;                 // 16-aligned
        const bool writer = (j0 == 0);             // one block per batch exports
        int base = 0;
#pragma unroll
        for (int c = 0; c < 8; ++c) {
            const int j = c * 64 + t;
            const int v = (mask[b * 512 + j] != 0);
            const unsigned long long bits = __ballot(v);
            const int pos = base + (int)__popcll(bits & ((1ull << t) - 1ull));
            if (j >= j0 && j < j0 + 16) posLoc[j - j0] = v ? pos : -1;
            base += (int)__popcll(bits);
        }
        if (writer && t == 0) { cnt_g[b] = base; cntS = base; }
    }

    const int u2 = (t & 63) * 2;                   // adjacent u pair
    const int wv = __builtin_amdgcn_readfirstlane(t >> 6);  // wave id 0..15
    const int dq = wv & 7;                         // d-eighth
    const int rh = wv >> 3;                        // row half (0: rows 0-7, 1: 8-15)
    const float* __restrict__ Wq = W + (size_t)dq * 64 * Uu;
    const float* __restrict__ xs = src + (size_t)(Rloc + rh * 8) * Dd + dq * 64; // uniform

    float acc[8][2];
#pragma unroll
    for (int r = 0; r < 8; ++r) { acc[r][0] = 0.f; acc[r][1] = 0.f; }

#pragma unroll 2
    for (int d4 = 0; d4 < 16; ++d4) {
        const int d = d4 * 4;
        const float2 w0 = *reinterpret_cast<const float2*>(Wq + (d + 0) * Uu + u2);
        const float2 w1 = *reinterpret_cast<const float2*>(Wq + (d + 1) * Uu + u2);
        const float2 w2 = *reinterpret_cast<const float2*>(Wq + (d + 2) * Uu + u2);
        const float2 w3 = *reinterpret_cast<const float2*>(Wq + (d + 3) * Uu + u2);
#pragma unroll
        for (int r = 0; r < 8; ++r) {
            // uniform address (block/wave/loop indices only) -> s_load broadcast
            const float4 xv = *reinterpret_cast<const float4*>(xs + r * Dd + d);
            acc[r][0] = fmaf(xv.x, w0.x, acc[r][0]);
            acc[r][1] = fmaf(xv.x, w0.y, acc[r][1]);
            acc[r][0] = fmaf(xv.y, w1.x, acc[r][0]);
            acc[r][1] = fmaf(xv.y, w1.y, acc[r][1]);
            acc[r][0] = fmaf(xv.z, w2.x, acc[r][0]);
            acc[r][1] = fmaf(xv.z, w2.y, acc[r][1]);
            acc[r][0] = fmaf(xv.w, w3.x, acc[r][0]);
            acc[r][1] = fmaf(xv.w, w3.y, acc[r][1]);
        }
    }

    {   // d-partial writes: float2, 2-way bank alias (free)
#pragma unroll
        for (int r = 0; r < 8; ++r) {
            float2 p; p.x = acc[r][0]; p.y = acc[r][1];
            *reinterpret_cast<float2*>(part + ((dq * 16 + rh * 8 + r) * 128) + u2) = p;
        }
    }
    __syncthreads();

    // reduce 8 d-partials, apply exp2(2log2e * .), store.
    // thread -> row r = t>>6 (0..15), u0 = (t&63)*2
    {
        const int r  = t >> 6;
        const int u0 = (t & 63) * 2;
        float s0 = 0.f, s1 = 0.f;
#pragma unroll
        for (int p = 0; p < 8; ++p) {
            const float2 pv = *reinterpret_cast<const float2*>(part + ((p * 16 + r) * 128) + u0);
            s0 += pv.x;
            s1 += pv.y;
        }
        float2 e;
        e.x = __builtin_amdgcn_exp2f(C2LOG2E * s0);
        e.y = __builtin_amdgcn_exp2f(C2LOG2E * s1);
        if (isQ) {
            *reinterpret_cast<float2*>(qf2 + (size_t)(Rloc + r) * Uu + u0) = e;
        } else {
            const int p = posLoc[r];
            if (p >= 0) {
                float* __restrict__ kb = kT + (size_t)(Rloc >> 9) * Uu * Tv;
                const int u4 = u0 >> 2;            // quad index
                const int c  = u0 & 3;             // 0 or 2
                *reinterpret_cast<float2*>(kb + ((size_t)u4 * Tv + p) * 4 + c) = e;
            }
        }
    }

    if (!isQ) {
        const int b = Rloc >> 9;
        // compact this block's masked value rows: vc[b][pos][:] = value[row][:]
        {
            const int r  = t >> 6;                 // 0..15
            const int di = t & 63;                 // 0..63
            const int p  = posLoc[r];
            if (p >= 0) {
                const float4* __restrict__ vsrc =
                    reinterpret_cast<const float4*>(value + (size_t)(Rloc + r) * Dd);
                float4* __restrict__ vdst =
                    reinterpret_cast<float4*>(vc + ((size_t)b * Tv + p) * Dd);
                vdst[di]      = vsrc[di];
                vdst[di + 64] = vsrc[di + 64];
            }
        }
        // writer block zeros tail rows [cnt, min(cnt+8,512)) for dense context
        if ((Rloc & 511) == 0) {
            const int cnt = cntS;                  // set before the barrier
            const int zr = t >> 7;                 // 0..7
            const int zd = t & 127;                // 0..127
            if (cnt + zr < 512) {
                float4* __restrict__ vdst =
                    reinterpret_cast<float4*>(vc + ((size_t)b * Tv + cnt + zr) * Dd);
                vdst[zd] = make_float4(0.f, 0.f, 0.f, 0.f);
            }
        }
    }
}

// ---------------------------------------------------------------------------
// Kernel B v12: R10/R14 attn body with ONE change: softmaxed weights go to a
// per-block GLOBAL scratch gw[bid][8][512] (coalesced stores) instead of LDS,
// and the context phase reads them via wave-UNIFORM s_load (scalar pipe) --
// removing the ~4096 ds_read_b128 weight broadcasts per CU (~20us of LDS-pipe
// time) from the context phase. Everything else identical to R14.
// ---------------------------------------------------------------------------
__global__ __launch_bounds__(1024, 8) void attn_kernel(
    const float* __restrict__ qf2, const float* __restrict__ kT,
    const float* __restrict__ vc,
    const int* __restrict__ cnt_g,
    const float* __restrict__ scale,
    float* __restrict__ gw,
    float* __restrict__ out)
{
    // XCD-aware bijective swizzle (512 % 8 == 0): XCD x <-> batch x
    const int bid = blockIdx.x;
    const int swz = (bid & 7) * 64 + (bid >> 3);
    const int r0 = swz * 8;                   // first query row (0..4088)
    const int b  = r0 >> 9;
    const int t  = threadIdx.x;               // 0..1023

    __shared__ float wbuf[4][8 * Tv];         // 64 KB: score quarters / ctx parks
    __shared__ float sums16[16];              // per (row, half) exp-sums

    const int cnt = cnt_g[b];                 // uniform -> s_load
    const int wvu = __builtin_amdgcn_readfirstlane(t >> 6); // wave id 0..15
    const int cntp4 = (cnt + 3) & ~3;
    float* __restrict__ gww = gw + (size_t)bid * (8 * Tv); // block's weight tile

    // ---- scores: 4 u-quarter wave-groups x 256 compact-j lanes ----
    {
        const int g   = wvu >> 2;             // u-quarter 0..3
        const int jc0 = t & 255;
        const float* __restrict__ qs = qf2 + (size_t)r0 * Uu + g * 32;  // uniform
        const float* __restrict__ ss = scale + g * 32;                  // uniform
        const float4* __restrict__ kb4 =
            reinterpret_cast<const float4*>(kT) + (size_t)b * 32 * Tv + (size_t)g * 8 * Tv;
        float* __restrict__ wr = wbuf[g];
        for (int jb = 0; jb < cnt; jb += 256) {
            const int jc = jb + jc0;
            if (jc < cnt) {
                v2f acc2[8];
#pragma unroll
                for (int i = 0; i < 8; ++i) acc2[i] = (v2f){0.f, 0.f};
#pragma unroll 2
                for (int u4 = 0; u4 < 8; ++u4) {
                    const float4 kv = kb4[(size_t)u4 * Tv + jc];
                    const v2f kv01 = {kv.x, kv.y};
                    const v2f kv23 = {kv.z, kv.w};
                    const v2f sv01 = *reinterpret_cast<const v2f*>(ss + u4 * 4);
                    const v2f sv23 = *reinterpret_cast<const v2f*>(ss + u4 * 4 + 2);
#pragma unroll
                    for (int i = 0; i < 8; ++i) {
                        const v2f qv01 = *reinterpret_cast<const v2f*>(qs + i * Uu + u4 * 4);
                        const v2f qv23 = *reinterpret_cast<const v2f*>(qs + i * Uu + u4 * 4 + 2);
                        const v2f one2 = {1.f, 1.f};
                        const v2f p01 = __builtin_elementwise_fma(kv01, qv01, one2); // pk
                        const v2f p23 = __builtin_elementwise_fma(kv23, qv23, one2); // pk
                        const float pp0 = p01.x * p01.y;
                        const float pp1 = p23.x * p23.y;
                        const float r   = __builtin_amdgcn_rcpf(pp0 * pp1);          // 1 trans
                        const float r01 = r * pp1;     // = 1/(p0*p1)
                        const float r23 = r * pp0;     // = 1/(p2*p3)
                        const v2f inv01 = {r01 * p01.y, r01 * p01.x};  // (1/p0, 1/p1)
                        const v2f inv23 = {r23 * p23.y, r23 * p23.x};  // (1/p2, 1/p3)
                        acc2[i] = __builtin_elementwise_fma(sv01, inv01, acc2[i]);   // pk
                        acc2[i] = __builtin_elementwise_fma(sv23, inv23, acc2[i]);   // pk
                    }
                }
#pragma unroll
                for (int i = 0; i < 8; ++i) wr[i * Tv + jc] = acc2[i].x + acc2[i].y;
            }
        }
    }
    __syncthreads();

    // ---- softmax, no max pass: wave wv -> row wv>>1, half wv&1 ----
    // weights are written to GLOBAL gww (coalesced b32), zero-padded.
    {
        const int ln = t & 63;
        const int i = wvu >> 1, h = wvu & 1;
        const float* __restrict__ rowA = wbuf[0] + i * Tv;
        const float* __restrict__ rowB = wbuf[1] + i * Tv;
        const float* __restrict__ rowC = wbuf[2] + i * Tv;
        const float* __restrict__ rowD = wbuf[3] + i * Tv;
        float* __restrict__ grow = gww + i * Tv;
        float sum = 0.f;
#pragma unroll
        for (int c = 0; c < 4; ++c) {
            const int e = ln + 64 * (h * 4 + c);
            if (e < cnt) {
                // score - const = -2*(sum of 4 quarter-partials); bounded -> safe
                const float ex = __builtin_amdgcn_exp2f(
                    -C2LOG2E * (rowA[e] + rowB[e] + rowC[e] + rowD[e]));
                grow[e] = ex;
                sum += ex;
            } else {
                grow[e] = 0.f;                 // pad for context float4 reads
            }
        }
#pragma unroll
        for (int off = 32; off; off >>= 1) sum += __shfl_xor(sum, off, 64);
        if (ln == 0) sums16[wvu] = sum;        // wvu = 2*i + h
    }
    __syncthreads();                           // drains vmcnt -> gw visible in L2

    // ---- context: dense compact V, weights via UNIFORM s_load (scalar pipe) ----
    const int g2 = wvu >> 2;                  // 0..3
    const int c  = t & 255;
    const int d0 = c * 2;
    const int chunk = ((cntp4 + 15) >> 4) << 2;            // 4-aligned quarter
    const int jbeg = g2 * chunk;
    const int jend = min(jbeg + chunk, cntp4);
    const float* __restrict__ vb = vc + (size_t)b * Tv * Dd + d0;
    const float* __restrict__ gwr = gww;       // uniform base
    v2f ax[8];
#pragma unroll
    for (int i = 0; i < 8; ++i) ax[i] = (v2f){0.f, 0.f};

#pragma unroll 2
    for (int jj = jbeg; jj < jend; jj += 4) {
        const v2f v0 = *reinterpret_cast<const v2f*>(vb + (size_t)(jj + 0) * Dd);
        const v2f v1 = *reinterpret_cast<const v2f*>(vb + (size_t)(jj + 1) * Dd);
        const v2f v2 = *reinterpret_cast<const v2f*>(vb + (size_t)(jj + 2) * Dd);
        const v2f v3 = *reinterpret_cast<const v2f*>(vb + (size_t)(jj + 3) * Dd);
#pragma unroll
        for (int i = 0; i < 8; ++i) {
            // uniform address (bid/loop indices only) -> s_load_dwordx4 broadcast
            const float4 wq = *reinterpret_cast<const float4*>(gwr + i * Tv + jj);
            ax[i] = __builtin_elementwise_fma((v2f){wq.x, wq.x}, v0, ax[i]);
            ax[i] = __builtin_elementwise_fma((v2f){wq.y, wq.y}, v1, ax[i]);
            ax[i] = __builtin_elementwise_fma((v2f){wq.z, wq.z}, v2, ax[i]);
            ax[i] = __builtin_elementwise_fma((v2f){wq.w, wq.w}, v3, ax[i]);
        }
    }

    if (g2 != 0) {                            // groups 1..3 park partials
#pragma unroll
        for (int i = 0; i < 8; ++i)
            *reinterpret_cast<v2f*>(wbuf[g2] + i * Tv + d0) = ax[i];
    }
    __syncthreads();
    if (g2 == 0) {                            // group 0 combines + stores
#pragma unroll
        for (int i = 0; i < 8; ++i) {
            const float inv = 1.0f / (sums16[2 * i] + sums16[2 * i + 1]);
            const v2f p1 = *reinterpret_cast<const v2f*>(wbuf[1] + i * Tv + d0);
            const v2f p2 = *reinterpret_cast<const v2f*>(wbuf[2] + i * Tv + d0);
            const v2f p3 = *reinterpret_cast<const v2f*>(wbuf[3] + i * Tv + d0);
            float2 o;
            o.x = (ax[i].x + p1.x + p2.x + p3.x) * inv;
            o.y = (ax[i].y + p1.y + p2.y + p3.y) * inv;
            *reinterpret_cast<float2*>(out + (size_t)(r0 + i) * Dd + d0) = o;
        }
    }
}

extern "C" void kernel_launch(void* const* d_in, const int* in_sizes, int n_in,
                              void* d_out, int out_size, void* d_ws, size_t ws_size,
                              hipStream_t stream)
{
    const float* query = (const float*)d_in[0];
    const float* key   = (const float*)d_in[1];
    const float* value = (const float*)d_in[2];
    const int*   mask  = (const int*)d_in[3];     // proven int32 (R2 bit-identical)
    const float* Wa    = (const float*)d_in[4];
    const float* Ua    = (const float*)d_in[5];
    const float* scale = (const float*)d_in[6];
    float* out = (float*)d_out;

    float* qf2   = (float*)d_ws;                  // [4096,128] = 2 MB (Eq)
    float* kT    = qf2 + Bb * Tq * Uu;            // [8][32][512] float4 = 2 MB (Ek)
    float* vc    = kT + Bb * Uu * Tv;             // [8][512][512] = 8 MB (compact V)
    float* gw    = vc + (size_t)Bb * Tv * Dd;     // [512][8][512] = 8 MB (weights)
    int*   cnt_g = (int*)(gw + (size_t)512 * 8 * Tv);  // [8]

    proj_kernel<<<(2 * Bb * Tq) / 16, 1024, 0, stream>>>(query, key, value, Wa, Ua,
                                                         mask, qf2, kT, vc, cnt_g);
    attn_kernel<<<(Bb * Tq) / 8, 1024, 0, stream>>>(qf2, kT, vc, cnt_g, scale,
                                                    gw, out);
}

// Round 16
// 150.036 us; speedup vs baseline: 1.2222x; 1.2222x over previous
//
#include <hip/hip_runtime.h>

// Problem constants (B=8, Tq=Tv=512, D=512, U=128)
constexpr int Bb = 8;
constexpr int Tq = 512;
constexpr int Tv = 512;
constexpr int Dd = 512;
constexpr int Uu = 128;
constexpr float C2LOG2E = 2.88539008177792681f;   // 2*log2(e)

typedef float v2f __attribute__((ext_vector_type(2)));

// ---------------------------------------------------------------------------
// Kernel A (R14 body; ONLY change: launch_bounds 8->4 waves/EU min, raising
// the VGPR cap 64->128. Occupancy is LDS-capped at 2 blocks/CU (64KB), so the
// extra register budget is free -- it lets the scheduler keep more W/x loads
// in flight). Projections + V-compaction, 16 rows/block, 1024 thr, 512 blocks.
// ---------------------------------------------------------------------------
__global__ __launch_bounds__(1024, 4) void proj_kernel(
    const float* __restrict__ query,
    const float* __restrict__ key,
    const float* __restrict__ value,
    const float* __restrict__ Wa,
    const float* __restrict__ Ua,
    const int* __restrict__ mask,
    float* __restrict__ qf2, float* __restrict__ kT,
    float* __restrict__ vc, int* __restrict__ cnt_g)
{
    const int R    = blockIdx.x * 16;              // 0..8191
    const bool isQ = R < Bb * Tq;
    const float* __restrict__ src = isQ ? query : key;
    const float* __restrict__ W   = isQ ? Wa : Ua;
    const int Rloc = isQ ? R : R - Bb * Tq;        // 0..4095

    __shared__ float part[8 * 16 * 128];           // 64 KB: part[dq][r][u]
    __shared__ int posLoc[16];
    __shared__ int cntS;
    const int t = threadIdx.x;                     // 0..1023

    if (!isQ && t < 64) {                          // wave-0 ballot scan -> pos
        const int b  = Rloc >> 9;
        const int j0 = Rloc & 511;                 // 16-aligned
        const bool writer = (j0 == 0);             // one block per batch exports
        int base = 0;
#pragma unroll
        for (int c = 0; c < 8; ++c) {
            const int j = c * 64 + t;
            const int v = (mask[b * 512 + j] != 0);
            const unsigned long long bits = __ballot(v);
            const int pos = base + (int)__popcll(bits & ((1ull << t) - 1ull));
            if (j >= j0 && j < j0 + 16) posLoc[j - j0] = v ? pos : -1;
            base += (int)__popcll(bits);
        }
        if (writer && t == 0) { cnt_g[b] = base; cntS = base; }
    }

    const int u2 = (t & 63) * 2;                   // adjacent u pair
    const int wv = __builtin_amdgcn_readfirstlane(t >> 6);  // wave id 0..15
    const int dq = wv & 7;                         // d-eighth
    const int rh = wv >> 3;                        // row half (0: rows 0-7, 1: 8-15)
    const float* __restrict__ Wq = W + (size_t)dq * 64 * Uu;
    const float* __restrict__ xs = src + (size_t)(Rloc + rh * 8) * Dd + dq * 64; // uniform

    float acc[8][2];
#pragma unroll
    for (int r = 0; r < 8; ++r) { acc[r][0] = 0.f; acc[r][1] = 0.f; }

#pragma unroll 2
    for (int d4 = 0; d4 < 16; ++d4) {
        const int d = d4 * 4;
        const float2 w0 = *reinterpret_cast<const float2*>(Wq + (d + 0) * Uu + u2);
        const float2 w1 = *reinterpret_cast<const float2*>(Wq + (d + 1) * Uu + u2);
        const float2 w2 = *reinterpret_cast<const float2*>(Wq + (d + 2) * Uu + u2);
        const float2 w3 = *reinterpret_cast<const float2*>(Wq + (d + 3) * Uu + u2);
#pragma unroll
        for (int r = 0; r < 8; ++r) {
            // uniform address (block/wave/loop indices only) -> s_load broadcast
            const float4 xv = *reinterpret_cast<const float4*>(xs + r * Dd + d);
            acc[r][0] = fmaf(xv.x, w0.x, acc[r][0]);
            acc[r][1] = fmaf(xv.x, w0.y, acc[r][1]);
            acc[r][0] = fmaf(xv.y, w1.x, acc[r][0]);
            acc[r][1] = fmaf(xv.y, w1.y, acc[r][1]);
            acc[r][0] = fmaf(xv.z, w2.x, acc[r][0]);
            acc[r][1] = fmaf(xv.z, w2.y, acc[r][1]);
            acc[r][0] = fmaf(xv.w, w3.x, acc[r][0]);
            acc[r][1] = fmaf(xv.w, w3.y, acc[r][1]);
        }
    }

    {   // d-partial writes: float2, 2-way bank alias (free)
#pragma unroll
        for (int r = 0; r < 8; ++r) {
            float2 p; p.x = acc[r][0]; p.y = acc[r][1];
            *reinterpret_cast<float2*>(part + ((dq * 16 + rh * 8 + r) * 128) + u2) = p;
        }
    }
    __syncthreads();

    // reduce 8 d-partials, apply exp2(2log2e * .), store.
    // thread -> row r = t>>6 (0..15), u0 = (t&63)*2
    {
        const int r  = t >> 6;
        const int u0 = (t & 63) * 2;
        float s0 = 0.f, s1 = 0.f;
#pragma unroll
        for (int p = 0; p < 8; ++p) {
            const float2 pv = *reinterpret_cast<const float2*>(part + ((p * 16 + r) * 128) + u0);
            s0 += pv.x;
            s1 += pv.y;
        }
        float2 e;
        e.x = __builtin_amdgcn_exp2f(C2LOG2E * s0);
        e.y = __builtin_amdgcn_exp2f(C2LOG2E * s1);
        if (isQ) {
            *reinterpret_cast<float2*>(qf2 + (size_t)(Rloc + r) * Uu + u0) = e;
        } else {
            const int p = posLoc[r];
            if (p >= 0) {
                float* __restrict__ kb = kT + (size_t)(Rloc >> 9) * Uu * Tv;
                const int u4 = u0 >> 2;            // quad index
                const int c  = u0 & 3;             // 0 or 2
                *reinterpret_cast<float2*>(kb + ((size_t)u4 * Tv + p) * 4 + c) = e;
            }
        }
    }

    if (!isQ) {
        const int b = Rloc >> 9;
        // compact this block's masked value rows: vc[b][pos][:] = value[row][:]
        {
            const int r  = t >> 6;                 // 0..15
            const int di = t & 63;                 // 0..63
            const int p  = posLoc[r];
            if (p >= 0) {
                const float4* __restrict__ vsrc =
                    reinterpret_cast<const float4*>(value + (size_t)(Rloc + r) * Dd);
                float4* __restrict__ vdst =
                    reinterpret_cast<float4*>(vc + ((size_t)b * Tv + p) * Dd);
                vdst[di]      = vsrc[di];
                vdst[di + 64] = vsrc[di + 64];
            }
        }
        // writer block zeros tail rows [cnt, min(cnt+8,512)) for dense context
        if ((Rloc & 511) == 0) {
            const int cnt = cntS;                  // set before the barrier
            const int zr = t >> 7;                 // 0..7
            const int zd = t & 127;                // 0..127
            if (cnt + zr < 512) {
                float4* __restrict__ vdst =
                    reinterpret_cast<float4*>(vc + ((size_t)b * Tv + cnt + zr) * Dd);
                vdst[zd] = make_float4(0.f, 0.f, 0.f, 0.f);
            }
        }
    }
}

// ---------------------------------------------------------------------------
// Kernel B (R14/R10 body; ONLY change: launch_bounds 8->4 waves/EU min ->
// VGPR cap 64->128; occupancy stays LDS-capped at 2 blocks/CU). Attention,
// 8 q-rows/block, 1024 threads, 512 blocks, bijective XCD swizzle.
// Score: u-quarter wave-groups, pk fp32 + quad rcp, s_load q/scale.
// Softmax: no max pass. Context: dense compact V, 4 j-groups, 2 d's/thread.
// ---------------------------------------------------------------------------
__global__ __launch_bounds__(1024, 4) void attn_kernel(
    const float* __restrict__ qf2, const float* __restrict__ kT,
    const float* __restrict__ vc,
    const int* __restrict__ cnt_g,
    const float* __restrict__ scale,
    float* __restrict__ out)
{
    // XCD-aware bijective swizzle (512 % 8 == 0): XCD x <-> batch x
    const int bid = blockIdx.x;
    const int swz = (bid & 7) * 64 + (bid >> 3);
    const int r0 = swz * 8;                   // first query row (0..4088)
    const int b  = r0 >> 9;
    const int t  = threadIdx.x;               // 0..1023

    __shared__ float wbuf[4][8 * Tv];         // 64 KB: score quarters / weights+parks
    __shared__ float sums16[16];              // per (row, half) exp-sums

    const int cnt = cnt_g[b];                 // uniform -> s_load
    const int wvu = __builtin_amdgcn_readfirstlane(t >> 6); // wave id 0..15
    const int cntp4 = (cnt + 3) & ~3;

    // ---- scores: 4 u-quarter wave-groups x 256 compact-j lanes ----
    {
        const int g   = wvu >> 2;             // u-quarter 0..3
        const int jc0 = t & 255;
        const float* __restrict__ qs = qf2 + (size_t)r0 * Uu + g * 32;  // uniform
        const float* __restrict__ ss = scale + g * 32;                  // uniform
        const float4* __restrict__ kb4 =
            reinterpret_cast<const float4*>(kT) + (size_t)b * 32 * Tv + (size_t)g * 8 * Tv;
        float* __restrict__ wr = wbuf[g];
        for (int jb = 0; jb < cnt; jb += 256) {
            const int jc = jb + jc0;
            if (jc < cnt) {
                v2f acc2[8];
#pragma unroll
                for (int i = 0; i < 8; ++i) acc2[i] = (v2f){0.f, 0.f};
#pragma unroll 2
                for (int u4 = 0; u4 < 8; ++u4) {
                    const float4 kv = kb4[(size_t)u4 * Tv + jc];
                    const v2f kv01 = {kv.x, kv.y};
                    const v2f kv23 = {kv.z, kv.w};
                    const v2f sv01 = *reinterpret_cast<const v2f*>(ss + u4 * 4);
                    const v2f sv23 = *reinterpret_cast<const v2f*>(ss + u4 * 4 + 2);
#pragma unroll
                    for (int i = 0; i < 8; ++i) {
                        const v2f qv01 = *reinterpret_cast<const v2f*>(qs + i * Uu + u4 * 4);
                        const v2f qv23 = *reinterpret_cast<const v2f*>(qs + i * Uu + u4 * 4 + 2);
                        const v2f one2 = {1.f, 1.f};
                        const v2f p01 = __builtin_elementwise_fma(kv01, qv01, one2); // pk
                        const v2f p23 = __builtin_elementwise_fma(kv23, qv23, one2); // pk
                        const float pp0 = p01.x * p01.y;
                        const float pp1 = p23.x * p23.y;
                        const float r   = __builtin_amdgcn_rcpf(pp0 * pp1);          // 1 trans
                        const float r01 = r * pp1;     // = 1/(p0*p1)
                        const float r23 = r * pp0;     // = 1/(p2*p3)
                        const v2f inv01 = {r01 * p01.y, r01 * p01.x};  // (1/p0, 1/p1)
                        const v2f inv23 = {r23 * p23.y, r23 * p23.x};  // (1/p2, 1/p3)
                        acc2[i] = __builtin_elementwise_fma(sv01, inv01, acc2[i]);   // pk
                        acc2[i] = __builtin_elementwise_fma(sv23, inv23, acc2[i]);   // pk
                    }
                }
#pragma unroll
                for (int i = 0; i < 8; ++i) wr[i * Tv + jc] = acc2[i].x + acc2[i].y;
            }
        }
    }
    __syncthreads();

    // ---- softmax, no max pass: wave wv -> row wv>>1, half wv&1 ----
    {
        const int ln = t & 63;
        const int i = wvu >> 1, h = wvu & 1;
        float* __restrict__ row        = wbuf[0] + i * Tv;
        const float* __restrict__ rowB = wbuf[1] + i * Tv;
        const float* __restrict__ rowC = wbuf[2] + i * Tv;
        const float* __restrict__ rowD = wbuf[3] + i * Tv;
        float sum = 0.f;
#pragma unroll
        for (int c = 0; c < 4; ++c) {
            const int e = ln + 64 * (h * 4 + c);
            if (e < cnt) {
                // score - const = -2*(sum of 4 quarter-partials); bounded -> safe
                const float ex = __builtin_amdgcn_exp2f(
                    -C2LOG2E * (row[e] + rowB[e] + rowC[e] + rowD[e]));
                row[e] = ex;
                sum += ex;
            } else {
                row[e] = 0.f;                  // pad for context float4 reads
            }
        }
#pragma unroll
        for (int off = 32; off; off >>= 1) sum += __shfl_xor(sum, off, 64);
        if (ln == 0) sums16[wvu] = sum;        // wvu = 2*i + h
    }
    __syncthreads();

    // ---- context: DENSE compact V, 4 wave-uniform j-groups, 2 d's/thread ----
    const int g2 = wvu >> 2;                  // 0..3
    const int c  = t & 255;
    const int d0 = c * 2;
    const int chunk = ((cntp4 + 15) >> 4) << 2;            // 4-aligned quarter
    const int jbeg = g2 * chunk;
    const int jend = min(jbeg + chunk, cntp4);
    const float* __restrict__ vb = vc + (size_t)b * Tv * Dd + d0;
    v2f ax[8];
#pragma unroll
    for (int i = 0; i < 8; ++i) ax[i] = (v2f){0.f, 0.f};

#pragma unroll 2
    for (int jj = jbeg; jj < jend; jj += 4) {
        const v2f v0 = *reinterpret_cast<const v2f*>(vb + (size_t)(jj + 0) * Dd);
        const v2f v1 = *reinterpret_cast<const v2f*>(vb + (size_t)(jj + 1) * Dd);
        const v2f v2 = *reinterpret_cast<const v2f*>(vb + (size_t)(jj + 2) * Dd);
        const v2f v3 = *reinterpret_cast<const v2f*>(vb + (size_t)(jj + 3) * Dd);
#pragma unroll
        for (int i = 0; i < 8; ++i) {
            const float4 wq = *reinterpret_cast<const float4*>(wbuf[0] + i * Tv + jj); // broadcast
            ax[i] = __builtin_elementwise_fma((v2f){wq.x, wq.x}, v0, ax[i]);
            ax[i] = __builtin_elementwise_fma((v2f){wq.y, wq.y}, v1, ax[i]);
            ax[i] = __builtin_elementwise_fma((v2f){wq.z, wq.z}, v2, ax[i]);
            ax[i] = __builtin_elementwise_fma((v2f){wq.w, wq.w}, v3, ax[i]);
        }
    }

    if (g2 != 0) {                            // groups 1..3 park partials
#pragma unroll
        for (int i = 0; i < 8; ++i)
            *reinterpret_cast<v2f*>(wbuf[g2] + i * Tv + d0) = ax[i];
    }
    __syncthreads();
    if (g2 == 0) {                            // group 0 combines + stores
#pragma unroll
        for (int i = 0; i < 8; ++i) {
            const float inv = 1.0f / (sums16[2 * i] + sums16[2 * i + 1]);
            const v2f p1 = *reinterpret_cast<const v2f*>(wbuf[1] + i * Tv + d0);
            const v2f p2 = *reinterpret_cast<const v2f*>(wbuf[2] + i * Tv + d0);
            const v2f p3 = *reinterpret_cast<const v2f*>(wbuf[3] + i * Tv + d0);
            float2 o;
            o.x = (ax[i].x + p1.x + p2.x + p3.x) * inv;
            o.y = (ax[i].y + p1.y + p2.y + p3.y) * inv;
            *reinterpret_cast<float2*>(out + (size_t)(r0 + i) * Dd + d0) = o;
        }
    }
}

extern "C" void kernel_launch(void* const* d_in, const int* in_sizes, int n_in,
                              void* d_out, int out_size, void* d_ws, size_t ws_size,
                              hipStream_t stream)
{
    const float* query = (const float*)d_in[0];
    const float* key   = (const float*)d_in[1];
    const float* value = (const float*)d_in[2];
    const int*   mask  = (const int*)d_in[3];     // proven int32 (R2 bit-identical)
    const float* Wa    = (const float*)d_in[4];
    const float* Ua    = (const float*)d_in[5];
    const float* scale = (const float*)d_in[6];
    float* out = (float*)d_out;

    float* qf2   = (float*)d_ws;                  // [4096,128] = 2 MB (Eq)
    float* kT    = qf2 + Bb * Tq * Uu;            // [8][32][512] float4 = 2 MB (Ek)
    float* vc    = kT + Bb * Uu * Tv;             // [8][512][512] = 8 MB (compact V)
    int*   cnt_g = (int*)(vc + (size_t)Bb * Tv * Dd);  // [8]

    proj_kernel<<<(2 * Bb * Tq) / 16, 1024, 0, stream>>>(query, key, value, Wa, Ua,
                                                         mask, qf2, kT, vc, cnt_g);
    attn_kernel<<<(Bb * Tq) / 8, 1024, 0, stream>>>(qf2, kT, vc, cnt_g, scale, out);
}

// Round 17
// 137.122 us; speedup vs baseline: 1.3374x; 1.0942x over previous
//
#include <hip/hip_runtime.h>

// Problem constants (B=8, Tq=Tv=512, D=512, U=128)
constexpr int Bb = 8;
constexpr int Tq = 512;
constexpr int Tv = 512;
constexpr int Dd = 512;
constexpr int Uu = 128;
constexpr float C2LOG2E = 2.88539008177792681f;   // 2*log2(e)

typedef float v2f __attribute__((ext_vector_type(2)));

// ---------------------------------------------------------------------------
// Kernel A (R14 best-measured body): projections + V-compaction, 16 rows/block,
// 1024 threads, 512 blocks (2 blocks/CU x 16 waves = 32 waves/CU, full).
// s_load x-fragments (wave-uniform), float2 W loads, 8-way LDS reduce.
// Outputs Eq/Ek = exp2(2log2e*proj); kT compact u4-interleaved
// kT[b][u4][pos][comp]; vc dense compact V with zeroed tail rows; cnt_g
// export from the j0==0 block. launch_bounds(1024,8): VGPR cap 64 keeps the
// compiler at 32 VGPR -> full wave occupancy (64-VGPR step halves waves).
// ---------------------------------------------------------------------------
__global__ __launch_bounds__(1024, 8) void proj_kernel(
    const float* __restrict__ query,
    const float* __restrict__ key,
    const float* __restrict__ value,
    const float* __restrict__ Wa,
    const float* __restrict__ Ua,
    const int* __restrict__ mask,
    float* __restrict__ qf2, float* __restrict__ kT,
    float* __restrict__ vc, int* __restrict__ cnt_g)
{
    const int R    = blockIdx.x * 16;              // 0..8191
    const bool isQ = R < Bb * Tq;
    const float* __restrict__ src = isQ ? query : key;
    const float* __restrict__ W   = isQ ? Wa : Ua;
    const int Rloc = isQ ? R : R - Bb * Tq;        // 0..4095

    __shared__ float part[8 * 16 * 128];           // 64 KB: part[dq][r][u]
    __shared__ int posLoc[16];
    __shared__ int cntS;
    const int t = threadIdx.x;                     // 0..1023

    if (!isQ && t < 64) {                          // wave-0 ballot scan -> pos
        const int b  = Rloc >> 9;
        const int j0 = Rloc & 511;                 // 16-aligned
        const bool writer = (j0 == 0);             // one block per batch exports
        int base = 0;
#pragma unroll
        for (int c = 0; c < 8; ++c) {
            const int j = c * 64 + t;
            const int v = (mask[b * 512 + j] != 0);
            const unsigned long long bits = __ballot(v);
            const int pos = base + (int)__popcll(bits & ((1ull << t) - 1ull));
            if (j >= j0 && j < j0 + 16) posLoc[j - j0] = v ? pos : -1;
            base += (int)__popcll(bits);
        }
        if (writer && t == 0) { cnt_g[b] = base; cntS = base; }
    }

    const int u2 = (t & 63) * 2;                   // adjacent u pair
    const int wv = __builtin_amdgcn_readfirstlane(t >> 6);  // wave id 0..15
    const int dq = wv & 7;                         // d-eighth
    const int rh = wv >> 3;                        // row half (0: rows 0-7, 1: 8-15)
    const float* __restrict__ Wq = W + (size_t)dq * 64 * Uu;
    const float* __restrict__ xs = src + (size_t)(Rloc + rh * 8) * Dd + dq * 64; // uniform

    float acc[8][2];
#pragma unroll
    for (int r = 0; r < 8; ++r) { acc[r][0] = 0.f; acc[r][1] = 0.f; }

#pragma unroll 2
    for (int d4 = 0; d4 < 16; ++d4) {
        const int d = d4 * 4;
        const float2 w0 = *reinterpret_cast<const float2*>(Wq + (d + 0) * Uu + u2);
        const float2 w1 = *reinterpret_cast<const float2*>(Wq + (d + 1) * Uu + u2);
        const float2 w2 = *reinterpret_cast<const float2*>(Wq + (d + 2) * Uu + u2);
        const float2 w3 = *reinterpret_cast<const float2*>(Wq + (d + 3) * Uu + u2);
#pragma unroll
        for (int r = 0; r < 8; ++r) {
            // uniform address (block/wave/loop indices only) -> s_load broadcast
            const float4 xv = *reinterpret_cast<const float4*>(xs + r * Dd + d);
            acc[r][0] = fmaf(xv.x, w0.x, acc[r][0]);
            acc[r][1] = fmaf(xv.x, w0.y, acc[r][1]);
            acc[r][0] = fmaf(xv.y, w1.x, acc[r][0]);
            acc[r][1] = fmaf(xv.y, w1.y, acc[r][1]);
            acc[r][0] = fmaf(xv.z, w2.x, acc[r][0]);
            acc[r][1] = fmaf(xv.z, w2.y, acc[r][1]);
            acc[r][0] = fmaf(xv.w, w3.x, acc[r][0]);
            acc[r][1] = fmaf(xv.w, w3.y, acc[r][1]);
        }
    }

    {   // d-partial writes: float2, 2-way bank alias (free)
#pragma unroll
        for (int r = 0; r < 8; ++r) {
            float2 p; p.x = acc[r][0]; p.y = acc[r][1];
            *reinterpret_cast<float2*>(part + ((dq * 16 + rh * 8 + r) * 128) + u2) = p;
        }
    }
    __syncthreads();

    // reduce 8 d-partials, apply exp2(2log2e * .), store.
    // thread -> row r = t>>6 (0..15), u0 = (t&63)*2
    {
        const int r  = t >> 6;
        const int u0 = (t & 63) * 2;
        float s0 = 0.f, s1 = 0.f;
#pragma unroll
        for (int p = 0; p < 8; ++p) {
            const float2 pv = *reinterpret_cast<const float2*>(part + ((p * 16 + r) * 128) + u0);
            s0 += pv.x;
            s1 += pv.y;
        }
        float2 e;
        e.x = __builtin_amdgcn_exp2f(C2LOG2E * s0);
        e.y = __builtin_amdgcn_exp2f(C2LOG2E * s1);
        if (isQ) {
            *reinterpret_cast<float2*>(qf2 + (size_t)(Rloc + r) * Uu + u0) = e;
        } else {
            const int p = posLoc[r];
            if (p >= 0) {
                float* __restrict__ kb = kT + (size_t)(Rloc >> 9) * Uu * Tv;
                const int u4 = u0 >> 2;            // quad index
                const int c  = u0 & 3;             // 0 or 2
                *reinterpret_cast<float2*>(kb + ((size_t)u4 * Tv + p) * 4 + c) = e;
            }
        }
    }

    if (!isQ) {
        const int b = Rloc >> 9;
        // compact this block's masked value rows: vc[b][pos][:] = value[row][:]
        {
            const int r  = t >> 6;                 // 0..15
            const int di = t & 63;                 // 0..63
            const int p  = posLoc[r];
            if (p >= 0) {
                const float4* __restrict__ vsrc =
                    reinterpret_cast<const float4*>(value + (size_t)(Rloc + r) * Dd);
                float4* __restrict__ vdst =
                    reinterpret_cast<float4*>(vc + ((size_t)b * Tv + p) * Dd);
                vdst[di]      = vsrc[di];
                vdst[di + 64] = vsrc[di + 64];
            }
        }
        // writer block zeros tail rows [cnt, min(cnt+8,512)) for dense context
        if ((Rloc & 511) == 0) {
            const int cnt = cntS;                  // set before the barrier
            const int zr = t >> 7;                 // 0..7
            const int zd = t & 127;                // 0..127
            if (cnt + zr < 512) {
                float4* __restrict__ vdst =
                    reinterpret_cast<float4*>(vc + ((size_t)b * Tv + cnt + zr) * Dd);
                vdst[zd] = make_float4(0.f, 0.f, 0.f, 0.f);
            }
        }
    }
}

// ---------------------------------------------------------------------------
// Kernel B (R14/R10 best-measured body): attention, 8 q-rows/block,
// 1024 threads, 512 blocks (2 blocks/CU x 16 waves = 32 waves/CU, full),
// bijective XCD swizzle (batch <-> XCD L2).
//   score  : u-quarter wave-groups (g=wvu>>2) x 256 compact-j lanes;
//            pk-fp32 + quad reciprocal (1 trans per 4 elements); q/scale via
//            wave-uniform s_load; partials -> wbuf[g].
//   softmax: no max pass (scores bounded by sum|scale| ~ 10); wave wv ->
//            (row wv>>1, half wv&1); weights in wbuf[0], zero-padded.
//   context: DENSE compact V (no jl indirection); 4 wave-uniform j-groups,
//            2 d's/thread (pk_fma); groups 1-3 park in wbuf[1..3], group 0
//            combines + stores.
// launch_bounds(1024,8): VGPR 32 -> full wave occupancy (the 64-VGPR step
// halves waves/CU -- R16 measured 48->65us when the cap was lifted).
// ---------------------------------------------------------------------------
__global__ __launch_bounds__(1024, 8) void attn_kernel(
    const float* __restrict__ qf2, const float* __restrict__ kT,
    const float* __restrict__ vc,
    const int* __restrict__ cnt_g,
    const float* __restrict__ scale,
    float* __restrict__ out)
{
    // XCD-aware bijective swizzle (512 % 8 == 0): XCD x <-> batch x
    const int bid = blockIdx.x;
    const int swz = (bid & 7) * 64 + (bid >> 3);
    const int r0 = swz * 8;                   // first query row (0..4088)
    const int b  = r0 >> 9;
    const int t  = threadIdx.x;               // 0..1023

    __shared__ float wbuf[4][8 * Tv];         // 64 KB: score quarters / weights+parks
    __shared__ float sums16[16];              // per (row, half) exp-sums

    const int cnt = cnt_g[b];                 // uniform -> s_load
    const int wvu = __builtin_amdgcn_readfirstlane(t >> 6); // wave id 0..15
    const int cntp4 = (cnt + 3) & ~3;

    // ---- scores: 4 u-quarter wave-groups x 256 compact-j lanes ----
    {
        const int g   = wvu >> 2;             // u-quarter 0..3
        const int jc0 = t & 255;
        const float* __restrict__ qs = qf2 + (size_t)r0 * Uu + g * 32;  // uniform
        const float* __restrict__ ss = scale + g * 32;                  // uniform
        const float4* __restrict__ kb4 =
            reinterpret_cast<const float4*>(kT) + (size_t)b * 32 * Tv + (size_t)g * 8 * Tv;
        float* __restrict__ wr = wbuf[g];
        for (int jb = 0; jb < cnt; jb += 256) {
            const int jc = jb + jc0;
            if (jc < cnt) {
                v2f acc2[8];
#pragma unroll
                for (int i = 0; i < 8; ++i) acc2[i] = (v2f){0.f, 0.f};
#pragma unroll 2
                for (int u4 = 0; u4 < 8; ++u4) {
                    const float4 kv = kb4[(size_t)u4 * Tv + jc];
                    const v2f kv01 = {kv.x, kv.y};
                    const v2f kv23 = {kv.z, kv.w};
                    const v2f sv01 = *reinterpret_cast<const v2f*>(ss + u4 * 4);
                    const v2f sv23 = *reinterpret_cast<const v2f*>(ss + u4 * 4 + 2);
#pragma unroll
                    for (int i = 0; i < 8; ++i) {
                        const v2f qv01 = *reinterpret_cast<const v2f*>(qs + i * Uu + u4 * 4);
                        const v2f qv23 = *reinterpret_cast<const v2f*>(qs + i * Uu + u4 * 4 + 2);
                        const v2f one2 = {1.f, 1.f};
                        const v2f p01 = __builtin_elementwise_fma(kv01, qv01, one2); // pk
                        const v2f p23 = __builtin_elementwise_fma(kv23, qv23, one2); // pk
                        const float pp0 = p01.x * p01.y;
                        const float pp1 = p23.x * p23.y;
                        const float r   = __builtin_amdgcn_rcpf(pp0 * pp1);          // 1 trans
                        const float r01 = r * pp1;     // = 1/(p0*p1)
                        const float r23 = r * pp0;     // = 1/(p2*p3)
                        const v2f inv01 = {r01 * p01.y, r01 * p01.x};  // (1/p0, 1/p1)
                        const v2f inv23 = {r23 * p23.y, r23 * p23.x};  // (1/p2, 1/p3)
                        acc2[i] = __builtin_elementwise_fma(sv01, inv01, acc2[i]);   // pk
                        acc2[i] = __builtin_elementwise_fma(sv23, inv23, acc2[i]);   // pk
                    }
                }
#pragma unroll
                for (int i = 0; i < 8; ++i) wr[i * Tv + jc] = acc2[i].x + acc2[i].y;
            }
        }
    }
    __syncthreads();

    // ---- softmax, no max pass: wave wv -> row wv>>1, half wv&1 ----
    {
        const int ln = t & 63;
        const int i = wvu >> 1, h = wvu & 1;
        float* __restrict__ row        = wbuf[0] + i * Tv;
        const float* __restrict__ rowB = wbuf[1] + i * Tv;
        const float* __restrict__ rowC = wbuf[2] + i * Tv;
        const float* __restrict__ rowD = wbuf[3] + i * Tv;
        float sum = 0.f;
#pragma unroll
        for (int c = 0; c < 4; ++c) {
            const int e = ln + 64 * (h * 4 + c);
            if (e < cnt) {
                // score - const = -2*(sum of 4 quarter-partials); bounded -> safe
                const float ex = __builtin_amdgcn_exp2f(
                    -C2LOG2E * (row[e] + rowB[e] + rowC[e] + rowD[e]));
                row[e] = ex;
                sum += ex;
            } else {
                row[e] = 0.f;                  // pad for context float4 reads
            }
        }
#pragma unroll
        for (int off = 32; off; off >>= 1) sum += __shfl_xor(sum, off, 64);
        if (ln == 0) sums16[wvu] = sum;        // wvu = 2*i + h
    }
    __syncthreads();

    // ---- context: DENSE compact V, 4 wave-uniform j-groups, 2 d's/thread ----
    const int g2 = wvu >> 2;                  // 0..3
    const int c  = t & 255;
    const int d0 = c * 2;
    const int chunk = ((cntp4 + 15) >> 4) << 2;            // 4-aligned quarter
    const int jbeg = g2 * chunk;
    const int jend = min(jbeg + chunk, cntp4);
    const float* __restrict__ vb = vc + (size_t)b * Tv * Dd + d0;
    v2f ax[8];
#pragma unroll
    for (int i = 0; i < 8; ++i) ax[i] = (v2f){0.f, 0.f};

#pragma unroll 2
    for (int jj = jbeg; jj < jend; jj += 4) {
        const v2f v0 = *reinterpret_cast<const v2f*>(vb + (size_t)(jj + 0) * Dd);
        const v2f v1 = *reinterpret_cast<const v2f*>(vb + (size_t)(jj + 1) * Dd);
        const v2f v2 = *reinterpret_cast<const v2f*>(vb + (size_t)(jj + 2) * Dd);
        const v2f v3 = *reinterpret_cast<const v2f*>(vb + (size_t)(jj + 3) * Dd);
#pragma unroll
        for (int i = 0; i < 8; ++i) {
            const float4 wq = *reinterpret_cast<const float4*>(wbuf[0] + i * Tv + jj); // broadcast
            ax[i] = __builtin_elementwise_fma((v2f){wq.x, wq.x}, v0, ax[i]);
            ax[i] = __builtin_elementwise_fma((v2f){wq.y, wq.y}, v1, ax[i]);
            ax[i] = __builtin_elementwise_fma((v2f){wq.z, wq.z}, v2, ax[i]);
            ax[i] = __builtin_elementwise_fma((v2f){wq.w, wq.w}, v3, ax[i]);
        }
    }

    if (g2 != 0) {                            // groups 1..3 park partials
#pragma unroll
        for (int i = 0; i < 8; ++i)
            *reinterpret_cast<v2f*>(wbuf[g2] + i * Tv + d0) = ax[i];
    }
    __syncthreads();
    if (g2 == 0) {                            // group 0 combines + stores
#pragma unroll
        for (int i = 0; i < 8; ++i) {
            const float inv = 1.0f / (sums16[2 * i] + sums16[2 * i + 1]);
            const v2f p1 = *reinterpret_cast<const v2f*>(wbuf[1] + i * Tv + d0);
            const v2f p2 = *reinterpret_cast<const v2f*>(wbuf[2] + i * Tv + d0);
            const v2f p3 = *reinterpret_cast<const v2f*>(wbuf[3] + i * Tv + d0);
            float2 o;
            o.x = (ax[i].x + p1.x + p2.x + p3.x) * inv;
            o.y = (ax[i].y + p1.y + p2.y + p3.y) * inv;
            *reinterpret_cast<float2*>(out + (size_t)(r0 + i) * Dd + d0) = o;
        }
    }
}

extern "C" void kernel_launch(void* const* d_in, const int* in_sizes, int n_in,
                              void* d_out, int out_size, void* d_ws, size_t ws_size,
                              hipStream_t stream)
{
    const float* query = (const float*)d_in[0];
    const float* key   = (const float*)d_in[1];
    const float* value = (const float*)d_in[2];
    const int*   mask  = (const int*)d_in[3];     // proven int32 (R2 bit-identical)
    const float* Wa    = (const float*)d_in[4];
    const float* Ua    = (const float*)d_in[5];
    const float* scale = (const float*)d_in[6];
    float* out = (float*)d_out;

    float* qf2   = (float*)d_ws;                  // [4096,128] = 2 MB (Eq)
    float* kT    = qf2 + Bb * Tq * Uu;            // [8][32][512] float4 = 2 MB (Ek)
    float* vc    = kT + Bb * Uu * Tv;             // [8][512][512] = 8 MB (compact V)
    int*   cnt_g = (int*)(vc + (size_t)Bb * Tv * Dd);  // [8]

    proj_kernel<<<(2 * Bb * Tq) / 16, 1024, 0, stream>>>(query, key, value, Wa, Ua,
                                                         mask, qf2, kT, vc, cnt_g);
    attn_kernel<<<(Bb * Tq) / 8, 1024, 0, stream>>>(qf2, kT, vc, cnt_g, scale, out);
}